// Round 7
// baseline (519.863 us; speedup 1.0000x reference)
//
#include <hip/hip_runtime.h>

#define F_IN 11
#define LN_EPS 1e-5f
#define BKT_SHIFT 8          // bucket = node >> 8 (256 nodes/bucket); requires N <= 131072
#define BKT_CAP 6144         // LDS edge cache per bucket (avg ~4092 for this graph)

typedef __attribute__((ext_vector_type(8))) short short8;
typedef __attribute__((ext_vector_type(4))) float f32x4;
typedef unsigned long long u64;

__device__ inline unsigned short f2bf(float f) {
  unsigned int u = __float_as_uint(f);
  unsigned int r = u + 0x7fffu + ((u >> 16) & 1u);
  return (unsigned short)(r >> 16);
}
__device__ inline float bf_lo(unsigned v) { return __uint_as_float(v << 16); }
__device__ inline float bf_hi(unsigned v) { return __uint_as_float(v & 0xffff0000u); }

#define ACC8(A, V) \
  A[0] += bf_lo(V.x); A[1] += bf_hi(V.x); A[2] += bf_lo(V.y); A[3] += bf_hi(V.y); \
  A[4] += bf_lo(V.z); A[5] += bf_hi(V.z); A[6] += bf_lo(V.w); A[7] += bf_hi(V.w);

// ---------------- CSR build: bucketed counting sort ----------------
__global__ __launch_bounds__(256) void k_bhist(const int* __restrict__ tgt,
                                               int* __restrict__ bcnt, int E, int NB) {
  __shared__ int h[512];
  int t = threadIdx.x;
  for (int i = t; i < NB; i += 256) h[i] = 0;
  __syncthreads();
  for (int i = blockIdx.x * 256 + t; i < E; i += gridDim.x * 256)
    atomicAdd(&h[tgt[i] >> BKT_SHIFT], 1);
  __syncthreads();
  for (int i = t; i < NB; i += 256) {
    int c = h[i];
    if (c) atomicAdd(&bcnt[i], c);
  }
}

__global__ void k_bscan(const int* __restrict__ bcnt, int* __restrict__ bOffs,
                        int* __restrict__ bcur, int NB) {
  __shared__ int s[512];
  int t = threadIdx.x;
  int v = (t < NB) ? bcnt[t] : 0;
  s[t] = v;
  __syncthreads();
  for (int d = 1; d < 512; d <<= 1) {
    int a = (t >= d) ? s[t - d] : 0;
    __syncthreads();
    s[t] += a;
    __syncthreads();
  }
  if (t < NB) {
    int e = s[t] - v;
    bOffs[t] = e;
    bcur[t] = e;
  }
}

// pack: (tgt & 255) << 24 | src   (needs src < 2^24, N <= 2^24)
__global__ __launch_bounds__(256) void k_bin(const int* __restrict__ src,
                                             const int* __restrict__ tgt,
                                             int* __restrict__ bcur,
                                             unsigned* __restrict__ tmp, int E, int NB) {
  __shared__ int cnt[512];
  __shared__ int gbase[512];
  int t = threadIdx.x;
  int base = blockIdx.x * 4096;
  for (int i = t; i < NB; i += 256) cnt[i] = 0;
  __syncthreads();
  int sv[16], tv[16], rk[16];
#pragma unroll
  for (int j = 0; j < 16; j++) {
    int idx = base + t + 256 * j;
    if (idx < E) {
      sv[j] = src[idx];
      tv[j] = tgt[idx];
      rk[j] = atomicAdd(&cnt[tv[j] >> BKT_SHIFT], 1);
    }
  }
  __syncthreads();
  for (int i = t; i < NB; i += 256) {
    int c = cnt[i];
    gbase[i] = c ? atomicAdd(&bcur[i], c) : 0;
  }
  __syncthreads();
#pragma unroll
  for (int j = 0; j < 16; j++) {
    int idx = base + t + 256 * j;
    if (idx < E)
      tmp[(size_t)gbase[tv[j] >> BKT_SHIFT] + rk[j]] =
          ((unsigned)(tv[j] & 255) << 24) | (unsigned)sv[j];
  }
}

__global__ __launch_bounds__(256) void k_bucket(
    const unsigned* __restrict__ tmp, const int* __restrict__ bOffs,
    const int* __restrict__ bcnt, int* __restrict__ deg, int* __restrict__ offs,
    int* __restrict__ csr, int N) {
  __shared__ unsigned eb[BKT_CAP];
  __shared__ int c1[256], lo[256], c2[256];
  int t = threadIdx.x;
  int b = blockIdx.x;
  int base_node = b << BKT_SHIFT;
  int cnt = bcnt[b], base_e = bOffs[b];
  c1[t] = 0;
  c2[t] = 0;
  for (int i = t; i < cnt && i < BKT_CAP; i += 256) eb[i] = tmp[base_e + i];
  __syncthreads();
  for (int i = t; i < cnt; i += 256) {
    unsigned e = (i < BKT_CAP) ? eb[i] : tmp[base_e + i];
    atomicAdd(&c1[e >> 24], 1);
  }
  __syncthreads();
  int myc = c1[t];
  lo[t] = myc;
  __syncthreads();
  for (int d = 1; d < 256; d <<= 1) {
    int a = (t >= d) ? lo[t - d] : 0;
    __syncthreads();
    lo[t] += a;
    __syncthreads();
  }
  int excl = lo[t] - myc;
  __syncthreads();
  lo[t] = excl;
  __syncthreads();
  int node = base_node + t;
  if (node < N) {
    deg[node] = myc;
    offs[node] = base_e + excl;
  }
  for (int i = t; i < cnt; i += 256) {
    unsigned e = (i < BKT_CAP) ? eb[i] : tmp[base_e + i];
    int sv = (int)(e & 0xffffffu);
    int lt = e >> 24;
    int r = atomicAdd(&c2[lt], 1);
    csr[base_e + lo[lt] + r] = sv;
  }
}

// ---------------- convert node features -> bf16 padded [N][16] (8 uints/row) ----------------
__global__ __launch_bounds__(256) void k_cvt(const float* __restrict__ nf,
                                             unsigned* __restrict__ nfb, int n) {
  int t = blockIdx.x * 256 + threadIdx.x;
  int node = t >> 3, li8 = t & 7;
  if (node >= n) return;
  int c0 = 2 * li8;
  float v0 = (c0 < F_IN) ? nf[(size_t)node * F_IN + c0] : 0.f;
  float v1 = (c0 + 1 < F_IN) ? nf[(size_t)node * F_IN + c0 + 1] : 0.f;
  nfb[(size_t)node * 8 + li8] = (unsigned)f2bf(v0) | ((unsigned)f2bf(v1) << 16);
}

// ---------------- fused layer 0: aggregate bf16[16] + linear(11->128)+LN+ReLU ----------------
// output x1 in CHUNKED layout: [8][n][16] bf16 (plane c holds features 16c..16c+15)
__global__ __launch_bounds__(256) void k_l0(
    const unsigned* __restrict__ nfb, const int* __restrict__ csr,
    const int* __restrict__ offs, const int* __restrict__ deg,
    const float* __restrict__ W, const float* __restrict__ b,
    const float* __restrict__ g, const float* __restrict__ be,
    unsigned* __restrict__ xout, int n) {
  __shared__ float Ws[128 * F_IN];
  __shared__ float bs[128], gs[128], bes[128];
  __shared__ float xs[8][F_IN + 1];
  int t = threadIdx.x;
  for (int i = t; i < 128 * F_IN; i += 256) Ws[i] = W[i];
  if (t < 128) { bs[t] = b[t]; gs[t] = g[t]; bes[t] = be[t]; }
  int jg = t & 31, ng = t >> 5;            // 8 nodes per iter, 32-lane group per node
  int sub = (t >> 3) & 3, li8 = t & 7;     // 4 edges in flight, 8 lanes per 32B row
  for (int base = blockIdx.x * 8; base < n; base += gridDim.x * 8) {
    int node = base + ng;
    int o = __builtin_nontemporal_load(&offs[node]);
    int d = __builtin_nontemporal_load(&deg[node]);
    float sx0 = 0.f, sy0 = 0.f, sx1 = 0.f, sy1 = 0.f;
    int e = 0;
    for (; e + 8 <= d; e += 8) {
      int i0 = __builtin_nontemporal_load(&csr[o + e + sub]);
      int i1 = __builtin_nontemporal_load(&csr[o + e + 4 + sub]);
      unsigned v0 = nfb[(size_t)i0 * 8 + li8];
      unsigned v1 = nfb[(size_t)i1 * 8 + li8];
      sx0 += bf_lo(v0); sy0 += bf_hi(v0);
      sx1 += bf_lo(v1); sy1 += bf_hi(v1);
    }
    for (; e < d; e += 4) {
      if (e + sub < d) {
        int i0 = __builtin_nontemporal_load(&csr[o + e + sub]);
        unsigned v = nfb[(size_t)i0 * 8 + li8];
        sx0 += bf_lo(v); sy0 += bf_hi(v);
      }
    }
    float sx = sx0 + sx1, sy = sy0 + sy1;
    sx += __shfl_xor(sx, 8, 64);  sx += __shfl_xor(sx, 16, 64);
    sy += __shfl_xor(sy, 8, 64);  sy += __shfl_xor(sy, 16, 64);
    float rd = (d > 0) ? 1.f / (float)d : 1.f;
    __syncthreads();
    if (sub == 0) {
      int c0 = 2 * li8;
      if (c0 < F_IN) xs[ng][c0] = sx * rd;
      if (c0 + 1 < F_IN) xs[ng][c0 + 1] = sy * rd;
    }
    __syncthreads();
    // linear 11->128 + LN + ReLU
    float bm = (d > 0) ? 1.f : 0.f;
    float acc[4];
#pragma unroll
    for (int i = 0; i < 4; i++) acc[i] = bm * bs[4 * jg + i];
#pragma unroll
    for (int k = 0; k < F_IN; k++) {
      float xv = xs[ng][k];
#pragma unroll
      for (int i = 0; i < 4; i++) acc[i] += xv * Ws[(4 * jg + i) * F_IN + k];
    }
    float s1 = acc[0] + acc[1] + acc[2] + acc[3];
    float s2 = acc[0]*acc[0] + acc[1]*acc[1] + acc[2]*acc[2] + acc[3]*acc[3];
#pragma unroll
    for (int m = 1; m < 32; m <<= 1) {
      s1 += __shfl_xor(s1, m, 64);
      s2 += __shfl_xor(s2, m, 64);
    }
    float mu = s1 * (1.f / 128.f);
    float var = s2 * (1.f / 128.f) - mu * mu;
    float rs = rsqrtf(var + LN_EPS);
    float o4[4];
#pragma unroll
    for (int i = 0; i < 4; i++)
      o4[i] = fmaxf((acc[i] - mu) * rs * gs[4 * jg + i] + bes[4 * jg + i], 0.f);
    uint2 pk;
    pk.x = (unsigned)f2bf(o4[0]) | ((unsigned)f2bf(o4[1]) << 16);
    pk.y = (unsigned)f2bf(o4[2]) | ((unsigned)f2bf(o4[3]) << 16);
    // chunked store: lane jg holds features 4jg..4jg+3 -> chunk jg>>2, uint2 slot jg&3
    ((uint2*)xout)[((size_t)(jg >> 2) * n + node) * 4 + (jg & 3)] = pk;
  }
}

// ---------------- aggregate 128-dim bf16 (mean), feature-chunked + XCD-affine ----------------
// X chunked [8][n][16] bf16; chunk = blockIdx & 7 -> XCD-local 3.2 MB working set.
// out row-major bf16 [n][128] (64 uints/row) for k_mlp.
__global__ __launch_bounds__(256) void k_agg128(
    const unsigned* __restrict__ X, const int* __restrict__ csr,
    const int* __restrict__ offs, const int* __restrict__ deg,
    unsigned* __restrict__ out, int n) {
  int t = threadIdx.x;
  int chunk = blockIdx.x & 7;
  int g = blockIdx.x >> 3;
  int w = t >> 6, lane = t & 63;
  int sub = lane >> 3, li = lane & 7;      // 8 lanes x 4B cover one 32B chunk-row; 8 edges in flight
  const unsigned* Xc = X + (size_t)chunk * n * 8;
  int stride = (gridDim.x >> 3) * 4;
  for (int node = g * 4 + w; node < n; node += stride) {
    int o = __builtin_nontemporal_load(&offs[node]);
    int d = __builtin_nontemporal_load(&deg[node]);
    float a0 = 0.f, a1 = 0.f, b0 = 0.f, b1 = 0.f;
    int e = 0;
    for (; e + 16 <= d; e += 16) {
      int i0 = __builtin_nontemporal_load(&csr[o + e + sub]);
      int i1 = __builtin_nontemporal_load(&csr[o + e + 8 + sub]);
      unsigned v0 = Xc[(size_t)i0 * 8 + li];
      unsigned v1 = Xc[(size_t)i1 * 8 + li];
      a0 += bf_lo(v0); a1 += bf_hi(v0);
      b0 += bf_lo(v1); b1 += bf_hi(v1);
    }
    for (; e < d; e += 8) {
      if (e + sub < d) {
        int i0 = __builtin_nontemporal_load(&csr[o + e + sub]);
        unsigned v = Xc[(size_t)i0 * 8 + li];
        a0 += bf_lo(v); a1 += bf_hi(v);
      }
    }
    a0 += b0;
    a1 += b1;
    a0 += __shfl_xor(a0, 8, 64); a0 += __shfl_xor(a0, 16, 64); a0 += __shfl_xor(a0, 32, 64);
    a1 += __shfl_xor(a1, 8, 64); a1 += __shfl_xor(a1, 16, 64); a1 += __shfl_xor(a1, 32, 64);
    float rd = (d > 0) ? 1.f / (float)d : 1.f;
    if (sub == 0) {
      unsigned pk = (unsigned)f2bf(a0 * rd) | ((unsigned)f2bf(a1 * rd) << 16);
      __builtin_nontemporal_store(pk, &out[(size_t)node * 64 + chunk * 8 + li]);
    }
  }
}

// ---------------- fused layer1+layer2 MFMA MLP ----------------
__global__ __launch_bounds__(256) void k_mlp(
    const unsigned* __restrict__ xa,
    const float* __restrict__ W1, const float* __restrict__ b1,
    const float* __restrict__ g1, const float* __restrict__ be1,
    const float* __restrict__ W2, const float* __restrict__ b2,
    const int* __restrict__ deg,
    unsigned* __restrict__ xt2, int n) {
  __shared__ short8 Wf1[32 * 64];
  __shared__ short8 Wf2[16 * 64];
  __shared__ unsigned bounce[4][1024];
  int t = threadIdx.x;
  int L = t & 63, w = t >> 6;
  for (int f = t; f < 2048; f += 256) {
    int tile = f >> 6, l = f & 63;
    int kt = tile >> 3, nt = tile & 7;
    const float* p = &W1[(nt * 16 + (l & 15)) * 128 + kt * 32 + (l >> 4) * 8];
    short8 v;
#pragma unroll
    for (int j = 0; j < 8; j++) v[j] = (short)f2bf(p[j]);
    Wf1[f] = v;
  }
  for (int f = t; f < 1024; f += 256) {
    int tile = f >> 6, l = f & 63;
    int kt = tile >> 2, nt = tile & 3;
    const float* p = &W2[(nt * 16 + (l & 15)) * 128 + kt * 32 + (l >> 4) * 8];
    short8 v;
#pragma unroll
    for (int j = 0; j < 8; j++) v[j] = (short)f2bf(p[j]);
    Wf2[f] = v;
  }
  int c = L & 15;
  float b1v[8], g1v[8], be1v[8], b2v[4];
#pragma unroll
  for (int nt = 0; nt < 8; nt++) {
    b1v[nt] = b1[nt * 16 + c];
    g1v[nt] = g1[nt * 16 + c];
    be1v[nt] = be1[nt * 16 + c];
  }
#pragma unroll
  for (int nt = 0; nt < 4; nt++) b2v[nt] = b2[nt * 16 + c];
  __syncthreads();

  int ntiles = n >> 4;
  unsigned* bw = bounce[w];
  int gg0 = (L >> 3) & 1;
  int odd = L & 1;
  for (int tile = blockIdx.x * 4 + w; tile < ntiles; tile += gridDim.x * 4) {
    int m0 = tile << 4;
    short8 a1[4];
    const char* xrow = (const char*)xa + (size_t)(m0 + c) * 256 + (L >> 4) * 16;
#pragma unroll
    for (int kt = 0; kt < 4; kt++) a1[kt] = *(const short8*)(xrow + kt * 64);
    f32x4 acc[8];
#pragma unroll
    for (int nt = 0; nt < 8; nt++) acc[nt] = (f32x4){0.f, 0.f, 0.f, 0.f};
#pragma unroll
    for (int kt = 0; kt < 4; kt++)
#pragma unroll
      for (int nt = 0; nt < 8; nt++)
        acc[nt] = __builtin_amdgcn_mfma_f32_16x16x32_bf16(
            a1[kt], Wf1[(kt * 8 + nt) * 64 + L], acc[nt], 0, 0, 0);
    int4 d4 = *(const int4*)&deg[m0 + (L >> 4) * 4];
    float mk[4];
    mk[0] = d4.x > 0 ? 1.f : 0.f; mk[1] = d4.y > 0 ? 1.f : 0.f;
    mk[2] = d4.z > 0 ? 1.f : 0.f; mk[3] = d4.w > 0 ? 1.f : 0.f;
#pragma unroll
    for (int nt = 0; nt < 8; nt++)
#pragma unroll
      for (int r = 0; r < 4; r++) acc[nt][r] += mk[r] * b1v[nt];
    float mu[4], rs[4];
#pragma unroll
    for (int r = 0; r < 4; r++) {
      float s1 = 0.f, s2 = 0.f;
#pragma unroll
      for (int nt = 0; nt < 8; nt++) { float v = acc[nt][r]; s1 += v; s2 += v * v; }
#pragma unroll
      for (int m = 1; m < 16; m <<= 1) {
        s1 += __shfl_xor(s1, m, 64);
        s2 += __shfl_xor(s2, m, 64);
      }
      float m_ = s1 * (1.f / 128.f);
      float var = s2 * (1.f / 128.f) - m_ * m_;
      mu[r] = m_;
      rs[r] = rsqrtf(var + LN_EPS);
    }
#pragma unroll
    for (int r = 0; r < 4; r++) {
      int rr = (L >> 4) * 4 + r;
#pragma unroll
      for (int p = 0; p < 4; p++) {
        float v0 = fmaxf((acc[2 * p][r] - mu[r]) * rs[r] * g1v[2 * p] + be1v[2 * p], 0.f);
        float v1 = fmaxf((acc[2 * p + 1][r] - mu[r]) * rs[r] * g1v[2 * p + 1] + be1v[2 * p + 1], 0.f);
        float u0 = __shfl_xor(v0, 1, 64);
        float u1 = __shfl_xor(v1, 1, 64);
        float w0 = odd ? u1 : v0;
        float w1 = odd ? v1 : u0;
        unsigned pk = (unsigned)f2bf(w0) | ((unsigned)f2bf(w1) << 16);
        int slot = rr + 16 * (gg0 + (odd ? 2 : 0));
        bw[p * 256 + slot * 4 + ((L & 6) >> 1)] = pk;
      }
    }
    short8 a2[4];
    const short8* br = (const short8*)bw;
#pragma unroll
    for (int kt = 0; kt < 4; kt++) a2[kt] = br[kt * 64 + L];
    f32x4 acc2[4];
#pragma unroll
    for (int nt = 0; nt < 4; nt++) acc2[nt] = (f32x4){0.f, 0.f, 0.f, 0.f};
#pragma unroll
    for (int kt = 0; kt < 4; kt++)
#pragma unroll
      for (int nt = 0; nt < 4; nt++)
        acc2[nt] = __builtin_amdgcn_mfma_f32_16x16x32_bf16(
            a2[kt], Wf2[(kt * 4 + nt) * 64 + L], acc2[nt], 0, 0, 0);
#pragma unroll
    for (int nt = 0; nt < 4; nt++)
#pragma unroll
      for (int r = 0; r < 4; r++) acc2[nt][r] += b2v[nt];
#pragma unroll
    for (int r = 0; r < 4; r++) {
      int rr = (L >> 4) * 4 + r;
#pragma unroll
      for (int p = 0; p < 2; p++) {
        float v0 = acc2[2 * p][r], v1 = acc2[2 * p + 1][r];
        float u0 = __shfl_xor(v0, 1, 64);
        float u1 = __shfl_xor(v1, 1, 64);
        float w0 = odd ? u1 : v0;
        float w1 = odd ? v1 : u0;
        unsigned pk = (unsigned)f2bf(w0) | ((unsigned)f2bf(w1) << 16);
        int j2 = 32 * p + (odd ? 16 : 0) + (L & 14);
        bw[rr * 32 + (j2 >> 1)] = pk;
      }
    }
    uint4* gout = (uint4*)((char*)xt2 + (size_t)m0 * 128);
    const uint4* brd = (const uint4*)bw;
    gout[L] = brd[L];
    gout[64 + L] = brd[64 + L];
  }
}

// ---------------- aggregate 64-dim bf16 (mean) + final LN, uint4 octet-groups ----------------
__global__ __launch_bounds__(256) void k_agg64_ln(
    const unsigned* __restrict__ X, const int* __restrict__ csr,
    const int* __restrict__ offs, const int* __restrict__ deg,
    const float* __restrict__ g, const float* __restrict__ be,
    float* __restrict__ out, int n) {
  int t = threadIdx.x;
  int lane = t & 31;                       // 32-lane group per node
  int sub = lane >> 3, li = lane & 7;      // 8 lanes x 16B cover one 128B row
  int node = blockIdx.x * 8 + (t >> 5);
  if (node >= n) return;
  int o = __builtin_nontemporal_load(&offs[node]);
  int d = __builtin_nontemporal_load(&deg[node]);
  const uint4* X4 = (const uint4*)X;
  float a[8], b[8];
#pragma unroll
  for (int i = 0; i < 8; i++) { a[i] = 0.f; b[i] = 0.f; }
  int e = 0;
  for (; e + 16 <= d; e += 16) {
    int i0 = __builtin_nontemporal_load(&csr[o + e + sub]);
    int i1 = __builtin_nontemporal_load(&csr[o + e + 4 + sub]);
    int i2 = __builtin_nontemporal_load(&csr[o + e + 8 + sub]);
    int i3 = __builtin_nontemporal_load(&csr[o + e + 12 + sub]);
    uint4 v0 = X4[(size_t)i0 * 8 + li];
    uint4 v1 = X4[(size_t)i1 * 8 + li];
    uint4 v2 = X4[(size_t)i2 * 8 + li];
    uint4 v3 = X4[(size_t)i3 * 8 + li];
    ACC8(a, v0); ACC8(b, v1); ACC8(a, v2); ACC8(b, v3);
  }
  for (; e < d; e += 4) {
    if (e + sub < d) {
      int i0 = __builtin_nontemporal_load(&csr[o + e + sub]);
      uint4 v = X4[(size_t)i0 * 8 + li];
      ACC8(a, v);
    }
  }
  float rd = (d > 0) ? 1.f / (float)d : 1.f;
  float v8[8];
  float s1 = 0.f, s2 = 0.f;
#pragma unroll
  for (int i = 0; i < 8; i++) {
    a[i] += b[i];
    a[i] += __shfl_xor(a[i], 8, 64);
    a[i] += __shfl_xor(a[i], 16, 64);
    v8[i] = a[i] * rd;
    s1 += v8[i];
    s2 += v8[i] * v8[i];
  }
#pragma unroll
  for (int m = 1; m < 8; m <<= 1) {        // reduce over the 8 li lanes
    s1 += __shfl_xor(s1, m, 64);
    s2 += __shfl_xor(s2, m, 64);
  }
  float mu = s1 * (1.f / 64.f);
  float var = s2 * (1.f / 64.f) - mu * mu;
  float rs = rsqrtf(var + LN_EPS);
  if (sub == 0) {
    float4 g0 = *(const float4*)&g[8 * li];
    float4 g1 = *(const float4*)&g[8 * li + 4];
    float4 e0 = *(const float4*)&be[8 * li];
    float4 e1 = *(const float4*)&be[8 * li + 4];
    float4 o0, o1;
    o0.x = (v8[0] - mu) * rs * g0.x + e0.x;
    o0.y = (v8[1] - mu) * rs * g0.y + e0.y;
    o0.z = (v8[2] - mu) * rs * g0.z + e0.z;
    o0.w = (v8[3] - mu) * rs * g0.w + e0.w;
    o1.x = (v8[4] - mu) * rs * g1.x + e1.x;
    o1.y = (v8[5] - mu) * rs * g1.y + e1.y;
    o1.z = (v8[6] - mu) * rs * g1.z + e1.z;
    o1.w = (v8[7] - mu) * rs * g1.w + e1.w;
    *(float4*)&out[(size_t)node * 64 + 8 * li] = o0;
    *(float4*)&out[(size_t)node * 64 + 8 * li + 4] = o1;
  }
}

extern "C" void kernel_launch(void* const* d_in, const int* in_sizes, int n_in,
                              void* d_out, int out_size, void* d_ws, size_t ws_size,
                              hipStream_t stream) {
  const float* nf  = (const float*)d_in[0];
  const int*   ei  = (const int*)d_in[1];
  const float* W0  = (const float*)d_in[2];
  const float* b0  = (const float*)d_in[3];
  const float* W1  = (const float*)d_in[4];
  const float* b1  = (const float*)d_in[5];
  const float* W2  = (const float*)d_in[6];
  const float* b2  = (const float*)d_in[7];
  const float* g0  = (const float*)d_in[8];
  const float* be0 = (const float*)d_in[9];
  const float* g1  = (const float*)d_in[10];
  const float* be1 = (const float*)d_in[11];
  const float* g2  = (const float*)d_in[12];
  const float* be2 = (const float*)d_in[13];
  float* out = (float*)d_out;

  int N = in_sizes[0] / F_IN;   // 100000
  int E = in_sizes[1] / 2;      // 1600000
  const int* src = ei;
  const int* tgt = ei + E;
  int NB = (N + 255) >> BKT_SHIFT;        // 391 buckets
  int NCH = (E + 4095) / 4096;            // 391 chunks

  char* w = (char*)d_ws;
  auto al = [](size_t x) { return (x + 255) & ~(size_t)255; };
  int* bcnt     = (int*)w;      w += al(512 * 4);
  int* bOffs    = (int*)w;      w += al(512 * 4);
  int* bcur     = (int*)w;      w += al(512 * 4);
  int* deg      = (int*)w;      w += al((size_t)N * 4);
  int* offs     = (int*)w;      w += al((size_t)N * 4);
  int* csr      = (int*)w;      w += al((size_t)E * 4);
  unsigned* tmp = (unsigned*)w; w += al((size_t)E * 4);
  unsigned* nfb = (unsigned*)w; w += al((size_t)N * 32);        // bf16 [N][16]
  unsigned* x1  = (unsigned*)w; w += al((size_t)N * 256);       // bf16 CHUNKED [8][N][16]
  unsigned* axg = (unsigned*)w; w += al((size_t)N * 256);       // bf16 row-major [N][128]
  unsigned* xt2 = (unsigned*)w; w += al((size_t)N * 128);       // bf16 row-major [N][64]

  hipMemsetAsync(bcnt, 0, 512 * 4, stream);

  // CSR build (bucketed counting sort; also produces deg/offs)
  k_bhist<<<256, 256, 0, stream>>>(tgt, bcnt, E, NB);
  k_bscan<<<1, 512, 0, stream>>>(bcnt, bOffs, bcur, NB);
  k_bin<<<NCH, 256, 0, stream>>>(src, tgt, bcur, tmp, E, NB);
  k_bucket<<<NB, 256, 0, stream>>>(tmp, bOffs, bcnt, deg, offs, csr, N);

  // input features -> padded bf16 [N][16]
  k_cvt<<<(N * 8 + 255) / 256, 256, 0, stream>>>(nf, nfb, N);

  // layer 0 fused: aggregate + linear+LN+ReLU -> chunked bf16 x1
  k_l0<<<(N + 7) / 8, 256, 0, stream>>>(nfb, csr, offs, deg, W0, b0, g0, be0, x1, N);

  // layer 1 aggregation: chunked gather (XCD-affine), row-major bf16 out
  k_agg128<<<16384, 256, 0, stream>>>(x1, csr, offs, deg, axg, N);

  // fused layer1 linear+LN+ReLU + layer2 linear (MFMA) -> bf16 xt2
  k_mlp<<<512, 256, 0, stream>>>(axg, W1, b1, g1, be1, W2, b2, deg, xt2, N);

  // layer 2 aggregation + final LN -> out
  k_agg64_ln<<<(N + 7) / 8, 256, 0, stream>>>(xt2, csr, offs, deg, g2, be2, out, N);
}

// Round 8
// 459.314 us; speedup vs baseline: 1.1318x; 1.1318x over previous
//
#include <hip/hip_runtime.h>

#define F_IN 11
#define LN_EPS 1e-5f
#define BKT_SHIFT 8          // bucket = node >> 8 (256 nodes/bucket); requires N <= 131072
#define BKT_CAP 6144         // LDS edge cache per bucket (avg ~4092 for this graph)

typedef __attribute__((ext_vector_type(8))) short short8;
typedef __attribute__((ext_vector_type(4))) float f32x4;
typedef unsigned long long u64;

__device__ inline unsigned short f2bf(float f) {
  unsigned int u = __float_as_uint(f);
  unsigned int r = u + 0x7fffu + ((u >> 16) & 1u);
  return (unsigned short)(r >> 16);
}
__device__ inline float bf_lo(unsigned v) { return __uint_as_float(v << 16); }
__device__ inline float bf_hi(unsigned v) { return __uint_as_float(v & 0xffff0000u); }

#define ACC8(A, V) \
  A[0] += bf_lo(V.x); A[1] += bf_hi(V.x); A[2] += bf_lo(V.y); A[3] += bf_hi(V.y); \
  A[4] += bf_lo(V.z); A[5] += bf_hi(V.z); A[6] += bf_lo(V.w); A[7] += bf_hi(V.w);

// ---------------- CSR build: bucketed counting sort ----------------
__global__ __launch_bounds__(256) void k_bhist(const int* __restrict__ tgt,
                                               int* __restrict__ bcnt, int E, int NB) {
  __shared__ int h[512];
  int t = threadIdx.x;
  for (int i = t; i < NB; i += 256) h[i] = 0;
  __syncthreads();
  for (int i = blockIdx.x * 256 + t; i < E; i += gridDim.x * 256)
    atomicAdd(&h[tgt[i] >> BKT_SHIFT], 1);
  __syncthreads();
  for (int i = t; i < NB; i += 256) {
    int c = h[i];
    if (c) atomicAdd(&bcnt[i], c);
  }
}

__global__ void k_bscan(const int* __restrict__ bcnt, int* __restrict__ bOffs,
                        int* __restrict__ bcur, int NB) {
  __shared__ int s[512];
  int t = threadIdx.x;
  int v = (t < NB) ? bcnt[t] : 0;
  s[t] = v;
  __syncthreads();
  for (int d = 1; d < 512; d <<= 1) {
    int a = (t >= d) ? s[t - d] : 0;
    __syncthreads();
    s[t] += a;
    __syncthreads();
  }
  if (t < NB) {
    int e = s[t] - v;
    bOffs[t] = e;
    bcur[t] = e;
  }
}

// pack: (tgt & 255) << 24 | src   (needs src < 2^24, N <= 2^24)
__global__ __launch_bounds__(256) void k_bin(const int* __restrict__ src,
                                             const int* __restrict__ tgt,
                                             int* __restrict__ bcur,
                                             unsigned* __restrict__ tmp, int E, int NB) {
  __shared__ int cnt[512];
  __shared__ int gbase[512];
  int t = threadIdx.x;
  int base = blockIdx.x * 4096;
  for (int i = t; i < NB; i += 256) cnt[i] = 0;
  __syncthreads();
  int sv[16], tv[16], rk[16];
#pragma unroll
  for (int j = 0; j < 16; j++) {
    int idx = base + t + 256 * j;
    if (idx < E) {
      sv[j] = src[idx];
      tv[j] = tgt[idx];
      rk[j] = atomicAdd(&cnt[tv[j] >> BKT_SHIFT], 1);
    }
  }
  __syncthreads();
  for (int i = t; i < NB; i += 256) {
    int c = cnt[i];
    gbase[i] = c ? atomicAdd(&bcur[i], c) : 0;
  }
  __syncthreads();
#pragma unroll
  for (int j = 0; j < 16; j++) {
    int idx = base + t + 256 * j;
    if (idx < E)
      tmp[(size_t)gbase[tv[j] >> BKT_SHIFT] + rk[j]] =
          ((unsigned)(tv[j] & 255) << 24) | (unsigned)sv[j];
  }
}

__global__ __launch_bounds__(256) void k_bucket(
    const unsigned* __restrict__ tmp, const int* __restrict__ bOffs,
    const int* __restrict__ bcnt, int* __restrict__ deg, int* __restrict__ offs,
    int* __restrict__ csr, int N) {
  __shared__ unsigned eb[BKT_CAP];
  __shared__ int c1[256], lo[256], c2[256];
  int t = threadIdx.x;
  int b = blockIdx.x;
  int base_node = b << BKT_SHIFT;
  int cnt = bcnt[b], base_e = bOffs[b];
  c1[t] = 0;
  c2[t] = 0;
  for (int i = t; i < cnt && i < BKT_CAP; i += 256) eb[i] = tmp[base_e + i];
  __syncthreads();
  for (int i = t; i < cnt; i += 256) {
    unsigned e = (i < BKT_CAP) ? eb[i] : tmp[base_e + i];
    atomicAdd(&c1[e >> 24], 1);
  }
  __syncthreads();
  int myc = c1[t];
  lo[t] = myc;
  __syncthreads();
  for (int d = 1; d < 256; d <<= 1) {
    int a = (t >= d) ? lo[t - d] : 0;
    __syncthreads();
    lo[t] += a;
    __syncthreads();
  }
  int excl = lo[t] - myc;
  __syncthreads();
  lo[t] = excl;
  __syncthreads();
  int node = base_node + t;
  if (node < N) {
    deg[node] = myc;
    offs[node] = base_e + excl;
  }
  for (int i = t; i < cnt; i += 256) {
    unsigned e = (i < BKT_CAP) ? eb[i] : tmp[base_e + i];
    int sv = (int)(e & 0xffffffu);
    int lt = e >> 24;
    int r = atomicAdd(&c2[lt], 1);
    csr[base_e + lo[lt] + r] = sv;
  }
}

// ---------------- convert node features -> bf16 padded [N][16] (8 uints/row) ----------------
__global__ __launch_bounds__(256) void k_cvt(const float* __restrict__ nf,
                                             unsigned* __restrict__ nfb, int n) {
  int t = blockIdx.x * 256 + threadIdx.x;
  int node = t >> 3, li8 = t & 7;
  if (node >= n) return;
  int c0 = 2 * li8;
  float v0 = (c0 < F_IN) ? nf[(size_t)node * F_IN + c0] : 0.f;
  float v1 = (c0 + 1 < F_IN) ? nf[(size_t)node * F_IN + c0 + 1] : 0.f;
  nfb[(size_t)node * 8 + li8] = (unsigned)f2bf(v0) | ((unsigned)f2bf(v1) << 16);
}

// ---------------- fused layer 0: aggregate bf16[16] + linear(11->128)+LN+ReLU ----------------
// output x1 in CHUNKED layout: [8][n][16] bf16 (plane c holds features 16c..16c+15)
__global__ __launch_bounds__(256) void k_l0(
    const unsigned* __restrict__ nfb, const int* __restrict__ csr,
    const int* __restrict__ offs, const int* __restrict__ deg,
    const float* __restrict__ W, const float* __restrict__ b,
    const float* __restrict__ g, const float* __restrict__ be,
    unsigned* __restrict__ xout, int n) {
  __shared__ float Ws[128 * F_IN];
  __shared__ float bs[128], gs[128], bes[128];
  __shared__ float xs[8][F_IN + 1];
  int t = threadIdx.x;
  for (int i = t; i < 128 * F_IN; i += 256) Ws[i] = W[i];
  if (t < 128) { bs[t] = b[t]; gs[t] = g[t]; bes[t] = be[t]; }
  int jg = t & 31, ng = t >> 5;            // 8 nodes per iter, 32-lane group per node
  int sub = (t >> 3) & 3, li8 = t & 7;     // 4 edges in flight, 8 lanes per 32B row
  for (int base = blockIdx.x * 8; base < n; base += gridDim.x * 8) {
    int node = base + ng;
    int o = __builtin_nontemporal_load(&offs[node]);
    int d = __builtin_nontemporal_load(&deg[node]);
    float sx0 = 0.f, sy0 = 0.f, sx1 = 0.f, sy1 = 0.f;
    int e = 0;
    for (; e + 8 <= d; e += 8) {
      int i0 = __builtin_nontemporal_load(&csr[o + e + sub]);
      int i1 = __builtin_nontemporal_load(&csr[o + e + 4 + sub]);
      unsigned v0 = nfb[(size_t)i0 * 8 + li8];
      unsigned v1 = nfb[(size_t)i1 * 8 + li8];
      sx0 += bf_lo(v0); sy0 += bf_hi(v0);
      sx1 += bf_lo(v1); sy1 += bf_hi(v1);
    }
    for (; e < d; e += 4) {
      if (e + sub < d) {
        int i0 = __builtin_nontemporal_load(&csr[o + e + sub]);
        unsigned v = nfb[(size_t)i0 * 8 + li8];
        sx0 += bf_lo(v); sy0 += bf_hi(v);
      }
    }
    float sx = sx0 + sx1, sy = sy0 + sy1;
    sx += __shfl_xor(sx, 8, 64);  sx += __shfl_xor(sx, 16, 64);
    sy += __shfl_xor(sy, 8, 64);  sy += __shfl_xor(sy, 16, 64);
    float rd = (d > 0) ? 1.f / (float)d : 1.f;
    __syncthreads();
    if (sub == 0) {
      int c0 = 2 * li8;
      if (c0 < F_IN) xs[ng][c0] = sx * rd;
      if (c0 + 1 < F_IN) xs[ng][c0 + 1] = sy * rd;
    }
    __syncthreads();
    // linear 11->128 + LN + ReLU
    float bm = (d > 0) ? 1.f : 0.f;
    float acc[4];
#pragma unroll
    for (int i = 0; i < 4; i++) acc[i] = bm * bs[4 * jg + i];
#pragma unroll
    for (int k = 0; k < F_IN; k++) {
      float xv = xs[ng][k];
#pragma unroll
      for (int i = 0; i < 4; i++) acc[i] += xv * Ws[(4 * jg + i) * F_IN + k];
    }
    float s1 = acc[0] + acc[1] + acc[2] + acc[3];
    float s2 = acc[0]*acc[0] + acc[1]*acc[1] + acc[2]*acc[2] + acc[3]*acc[3];
#pragma unroll
    for (int m = 1; m < 32; m <<= 1) {
      s1 += __shfl_xor(s1, m, 64);
      s2 += __shfl_xor(s2, m, 64);
    }
    float mu = s1 * (1.f / 128.f);
    float var = s2 * (1.f / 128.f) - mu * mu;
    float rs = rsqrtf(var + LN_EPS);
    float o4[4];
#pragma unroll
    for (int i = 0; i < 4; i++)
      o4[i] = fmaxf((acc[i] - mu) * rs * gs[4 * jg + i] + bes[4 * jg + i], 0.f);
    uint2 pk;
    pk.x = (unsigned)f2bf(o4[0]) | ((unsigned)f2bf(o4[1]) << 16);
    pk.y = (unsigned)f2bf(o4[2]) | ((unsigned)f2bf(o4[3]) << 16);
    // chunked store: lane jg holds features 4jg..4jg+3 -> chunk jg>>2, uint2 slot jg&3
    ((uint2*)xout)[((size_t)(jg >> 2) * n + node) * 4 + (jg & 3)] = pk;
  }
}

// ---------------- aggregate 128-dim bf16 (mean), chunked + XCD-affine, lane-pair/node ----------------
// X chunked [8][n][16] bf16 (32B rows); chunk = blockIdx & 7 -> 3.2 MB XCD-local set.
// Lane-pair per node: each lane serially accumulates its 16B half; NO cross-lane reduce.
// out row-major bf16 [n][128] (16 uint4/row) for k_mlp.
__global__ __launch_bounds__(256) void k_agg128(
    const unsigned* __restrict__ X, const int* __restrict__ csr,
    const int* __restrict__ offs, const int* __restrict__ deg,
    unsigned* __restrict__ out, int n) {
  int t = threadIdx.x;
  int chunk = blockIdx.x & 7;
  int gi = blockIdx.x >> 3;
  int w = t >> 6, lane = t & 63;
  int pr = lane >> 1, hi = lane & 1;       // 32 nodes/wave, lane-pair splits 32B row
  int node = gi * 128 + w * 32 + pr;
  if (node >= n) return;
  const uint4* Xc4 = (const uint4*)X + (size_t)chunk * n * 2;
  int o = __builtin_nontemporal_load(&offs[node]);
  int d = __builtin_nontemporal_load(&deg[node]);
  float a[8], b[8];
#pragma unroll
  for (int i = 0; i < 8; i++) { a[i] = 0.f; b[i] = 0.f; }
  int e = 0;
  for (; e + 4 <= d; e += 4) {
    int i0 = __builtin_nontemporal_load(&csr[o + e]);
    int i1 = __builtin_nontemporal_load(&csr[o + e + 1]);
    int i2 = __builtin_nontemporal_load(&csr[o + e + 2]);
    int i3 = __builtin_nontemporal_load(&csr[o + e + 3]);
    uint4 v0 = Xc4[(size_t)i0 * 2 + hi];
    uint4 v1 = Xc4[(size_t)i1 * 2 + hi];
    uint4 v2 = Xc4[(size_t)i2 * 2 + hi];
    uint4 v3 = Xc4[(size_t)i3 * 2 + hi];
    ACC8(a, v0); ACC8(b, v1); ACC8(a, v2); ACC8(b, v3);
  }
  for (; e < d; ++e) {
    int i0 = __builtin_nontemporal_load(&csr[o + e]);
    uint4 v = Xc4[(size_t)i0 * 2 + hi];
    ACC8(a, v);
  }
  float rd = (d > 0) ? 1.f / (float)d : 1.f;
  uint4 pk;
  pk.x = (unsigned)f2bf((a[0] + b[0]) * rd) | ((unsigned)f2bf((a[1] + b[1]) * rd) << 16);
  pk.y = (unsigned)f2bf((a[2] + b[2]) * rd) | ((unsigned)f2bf((a[3] + b[3]) * rd) << 16);
  pk.z = (unsigned)f2bf((a[4] + b[4]) * rd) | ((unsigned)f2bf((a[5] + b[5]) * rd) << 16);
  pk.w = (unsigned)f2bf((a[6] + b[6]) * rd) | ((unsigned)f2bf((a[7] + b[7]) * rd) << 16);
  ((uint4*)out)[(size_t)node * 16 + chunk * 2 + hi] = pk;
}

// ---------------- fused layer1+layer2 MFMA MLP (writes xt2 CHUNKED [4][n][16]) ----------------
__global__ __launch_bounds__(256) void k_mlp(
    const unsigned* __restrict__ xa,
    const float* __restrict__ W1, const float* __restrict__ b1,
    const float* __restrict__ g1, const float* __restrict__ be1,
    const float* __restrict__ W2, const float* __restrict__ b2,
    const int* __restrict__ deg,
    unsigned* __restrict__ xt2, int n) {
  __shared__ short8 Wf1[32 * 64];
  __shared__ short8 Wf2[16 * 64];
  __shared__ unsigned bounce[4][1024];
  int t = threadIdx.x;
  int L = t & 63, w = t >> 6;
  for (int f = t; f < 2048; f += 256) {
    int tile = f >> 6, l = f & 63;
    int kt = tile >> 3, nt = tile & 7;
    const float* p = &W1[(nt * 16 + (l & 15)) * 128 + kt * 32 + (l >> 4) * 8];
    short8 v;
#pragma unroll
    for (int j = 0; j < 8; j++) v[j] = (short)f2bf(p[j]);
    Wf1[f] = v;
  }
  for (int f = t; f < 1024; f += 256) {
    int tile = f >> 6, l = f & 63;
    int kt = tile >> 2, nt = tile & 3;
    const float* p = &W2[(nt * 16 + (l & 15)) * 128 + kt * 32 + (l >> 4) * 8];
    short8 v;
#pragma unroll
    for (int j = 0; j < 8; j++) v[j] = (short)f2bf(p[j]);
    Wf2[f] = v;
  }
  int c = L & 15;
  float b1v[8], g1v[8], be1v[8], b2v[4];
#pragma unroll
  for (int nt = 0; nt < 8; nt++) {
    b1v[nt] = b1[nt * 16 + c];
    g1v[nt] = g1[nt * 16 + c];
    be1v[nt] = be1[nt * 16 + c];
  }
#pragma unroll
  for (int nt = 0; nt < 4; nt++) b2v[nt] = b2[nt * 16 + c];
  __syncthreads();

  int ntiles = n >> 4;
  unsigned* bw = bounce[w];
  int gg0 = (L >> 3) & 1;
  int odd = L & 1;
  for (int tile = blockIdx.x * 4 + w; tile < ntiles; tile += gridDim.x * 4) {
    int m0 = tile << 4;
    short8 a1[4];
    const char* xrow = (const char*)xa + (size_t)(m0 + c) * 256 + (L >> 4) * 16;
#pragma unroll
    for (int kt = 0; kt < 4; kt++) a1[kt] = *(const short8*)(xrow + kt * 64);
    f32x4 acc[8];
#pragma unroll
    for (int nt = 0; nt < 8; nt++) acc[nt] = (f32x4){0.f, 0.f, 0.f, 0.f};
#pragma unroll
    for (int kt = 0; kt < 4; kt++)
#pragma unroll
      for (int nt = 0; nt < 8; nt++)
        acc[nt] = __builtin_amdgcn_mfma_f32_16x16x32_bf16(
            a1[kt], Wf1[(kt * 8 + nt) * 64 + L], acc[nt], 0, 0, 0);
    int4 d4 = *(const int4*)&deg[m0 + (L >> 4) * 4];
    float mk[4];
    mk[0] = d4.x > 0 ? 1.f : 0.f; mk[1] = d4.y > 0 ? 1.f : 0.f;
    mk[2] = d4.z > 0 ? 1.f : 0.f; mk[3] = d4.w > 0 ? 1.f : 0.f;
#pragma unroll
    for (int nt = 0; nt < 8; nt++)
#pragma unroll
      for (int r = 0; r < 4; r++) acc[nt][r] += mk[r] * b1v[nt];
    float mu[4], rs[4];
#pragma unroll
    for (int r = 0; r < 4; r++) {
      float s1 = 0.f, s2 = 0.f;
#pragma unroll
      for (int nt = 0; nt < 8; nt++) { float v = acc[nt][r]; s1 += v; s2 += v * v; }
#pragma unroll
      for (int m = 1; m < 16; m <<= 1) {
        s1 += __shfl_xor(s1, m, 64);
        s2 += __shfl_xor(s2, m, 64);
      }
      float m_ = s1 * (1.f / 128.f);
      float var = s2 * (1.f / 128.f) - m_ * m_;
      mu[r] = m_;
      rs[r] = rsqrtf(var + LN_EPS);
    }
#pragma unroll
    for (int r = 0; r < 4; r++) {
      int rr = (L >> 4) * 4 + r;
#pragma unroll
      for (int p = 0; p < 4; p++) {
        float v0 = fmaxf((acc[2 * p][r] - mu[r]) * rs[r] * g1v[2 * p] + be1v[2 * p], 0.f);
        float v1 = fmaxf((acc[2 * p + 1][r] - mu[r]) * rs[r] * g1v[2 * p + 1] + be1v[2 * p + 1], 0.f);
        float u0 = __shfl_xor(v0, 1, 64);
        float u1 = __shfl_xor(v1, 1, 64);
        float w0 = odd ? u1 : v0;
        float w1 = odd ? v1 : u0;
        unsigned pk = (unsigned)f2bf(w0) | ((unsigned)f2bf(w1) << 16);
        int slot = rr + 16 * (gg0 + (odd ? 2 : 0));
        bw[p * 256 + slot * 4 + ((L & 6) >> 1)] = pk;
      }
    }
    short8 a2[4];
    const short8* br = (const short8*)bw;
#pragma unroll
    for (int kt = 0; kt < 4; kt++) a2[kt] = br[kt * 64 + L];
    f32x4 acc2[4];
#pragma unroll
    for (int nt = 0; nt < 4; nt++) acc2[nt] = (f32x4){0.f, 0.f, 0.f, 0.f};
#pragma unroll
    for (int kt = 0; kt < 4; kt++)
#pragma unroll
      for (int nt = 0; nt < 4; nt++)
        acc2[nt] = __builtin_amdgcn_mfma_f32_16x16x32_bf16(
            a2[kt], Wf2[(kt * 4 + nt) * 64 + L], acc2[nt], 0, 0, 0);
#pragma unroll
    for (int nt = 0; nt < 4; nt++)
#pragma unroll
      for (int r = 0; r < 4; r++) acc2[nt][r] += b2v[nt];
#pragma unroll
    for (int r = 0; r < 4; r++) {
      int rr = (L >> 4) * 4 + r;
#pragma unroll
      for (int p = 0; p < 2; p++) {
        float v0 = acc2[2 * p][r], v1 = acc2[2 * p + 1][r];
        float u0 = __shfl_xor(v0, 1, 64);
        float u1 = __shfl_xor(v1, 1, 64);
        float w0 = odd ? u1 : v0;
        float w1 = odd ? v1 : u0;
        unsigned pk = (unsigned)f2bf(w0) | ((unsigned)f2bf(w1) << 16);
        int j2 = 32 * p + (odd ? 16 : 0) + (L & 14);
        bw[rr * 32 + (j2 >> 1)] = pk;
      }
    }
    // chunked store: bw row-major [16 rows][32 uints]; plane ch holds uints 8ch..8ch+7
    const uint4* brd = (const uint4*)bw;
#pragma unroll
    for (int i = 0; i < 2; i++) {
      int flat = i * 64 + L;               // 0..127 uint4s
      int row = flat >> 3, slot = flat & 7;
      int ch = slot >> 1, hh = slot & 1;
      ((uint4*)xt2)[((size_t)ch * n + m0 + row) * 2 + hh] = brd[flat];
    }
  }
}

// ---------------- aggregate 64-dim bf16 (mean), chunked [4][n][16], lane-pair/node ----------------
__global__ __launch_bounds__(256) void k_agg64(
    const unsigned* __restrict__ X, const int* __restrict__ csr,
    const int* __restrict__ offs, const int* __restrict__ deg,
    unsigned* __restrict__ ybuf, int n) {
  int t = threadIdx.x;
  int chunk = blockIdx.x & 3;
  int gi = blockIdx.x >> 2;
  int w = t >> 6, lane = t & 63;
  int pr = lane >> 1, hi = lane & 1;
  int node = gi * 128 + w * 32 + pr;
  if (node >= n) return;
  const uint4* Xc4 = (const uint4*)X + (size_t)chunk * n * 2;
  int o = __builtin_nontemporal_load(&offs[node]);
  int d = __builtin_nontemporal_load(&deg[node]);
  float a[8], b[8];
#pragma unroll
  for (int i = 0; i < 8; i++) { a[i] = 0.f; b[i] = 0.f; }
  int e = 0;
  for (; e + 4 <= d; e += 4) {
    int i0 = __builtin_nontemporal_load(&csr[o + e]);
    int i1 = __builtin_nontemporal_load(&csr[o + e + 1]);
    int i2 = __builtin_nontemporal_load(&csr[o + e + 2]);
    int i3 = __builtin_nontemporal_load(&csr[o + e + 3]);
    uint4 v0 = Xc4[(size_t)i0 * 2 + hi];
    uint4 v1 = Xc4[(size_t)i1 * 2 + hi];
    uint4 v2 = Xc4[(size_t)i2 * 2 + hi];
    uint4 v3 = Xc4[(size_t)i3 * 2 + hi];
    ACC8(a, v0); ACC8(b, v1); ACC8(a, v2); ACC8(b, v3);
  }
  for (; e < d; ++e) {
    int i0 = __builtin_nontemporal_load(&csr[o + e]);
    uint4 v = Xc4[(size_t)i0 * 2 + hi];
    ACC8(a, v);
  }
  float rd = (d > 0) ? 1.f / (float)d : 1.f;
  uint4 pk;
  pk.x = (unsigned)f2bf((a[0] + b[0]) * rd) | ((unsigned)f2bf((a[1] + b[1]) * rd) << 16);
  pk.y = (unsigned)f2bf((a[2] + b[2]) * rd) | ((unsigned)f2bf((a[3] + b[3]) * rd) << 16);
  pk.z = (unsigned)f2bf((a[4] + b[4]) * rd) | ((unsigned)f2bf((a[5] + b[5]) * rd) << 16);
  pk.w = (unsigned)f2bf((a[6] + b[6]) * rd) | ((unsigned)f2bf((a[7] + b[7]) * rd) << 16);
  ((uint4*)ybuf)[((size_t)chunk * n + node) * 2 + hi] = pk;
}

// ---------------- final LN over chunked [4][n][16] bf16 -> fp32 out [n][64] ----------------
__global__ __launch_bounds__(256) void k_ln64(
    const unsigned* __restrict__ ybuf, const float* __restrict__ g,
    const float* __restrict__ be, float* __restrict__ out, int n) {
  int t = threadIdx.x;
  int node = blockIdx.x * 32 + (t >> 3);
  int li = t & 7;                          // 8 lanes per node
  int chunk = li >> 1, hi = li & 1;        // features chunk*16 + hi*8 .. +7
  if (node >= n) return;
  uint4 v = ((const uint4*)ybuf)[((size_t)chunk * n + node) * 2 + hi];
  float x[8];
  x[0] = bf_lo(v.x); x[1] = bf_hi(v.x); x[2] = bf_lo(v.y); x[3] = bf_hi(v.y);
  x[4] = bf_lo(v.z); x[5] = bf_hi(v.z); x[6] = bf_lo(v.w); x[7] = bf_hi(v.w);
  float s1 = 0.f, s2 = 0.f;
#pragma unroll
  for (int i = 0; i < 8; i++) { s1 += x[i]; s2 += x[i] * x[i]; }
#pragma unroll
  for (int m = 1; m < 8; m <<= 1) {
    s1 += __shfl_xor(s1, m, 64);
    s2 += __shfl_xor(s2, m, 64);
  }
  float mu = s1 * (1.f / 64.f);
  float var = s2 * (1.f / 64.f) - mu * mu;
  float rs = rsqrtf(var + LN_EPS);
  int f0 = chunk * 16 + hi * 8;
  float4 g0 = *(const float4*)&g[f0];
  float4 g1 = *(const float4*)&g[f0 + 4];
  float4 e0 = *(const float4*)&be[f0];
  float4 e1 = *(const float4*)&be[f0 + 4];
  float4 o0, o1;
  o0.x = (x[0] - mu) * rs * g0.x + e0.x;
  o0.y = (x[1] - mu) * rs * g0.y + e0.y;
  o0.z = (x[2] - mu) * rs * g0.z + e0.z;
  o0.w = (x[3] - mu) * rs * g0.w + e0.w;
  o1.x = (x[4] - mu) * rs * g1.x + e1.x;
  o1.y = (x[5] - mu) * rs * g1.y + e1.y;
  o1.z = (x[6] - mu) * rs * g1.z + e1.z;
  o1.w = (x[7] - mu) * rs * g1.w + e1.w;
  *(float4*)&out[(size_t)node * 64 + f0] = o0;
  *(float4*)&out[(size_t)node * 64 + f0 + 4] = o1;
}

extern "C" void kernel_launch(void* const* d_in, const int* in_sizes, int n_in,
                              void* d_out, int out_size, void* d_ws, size_t ws_size,
                              hipStream_t stream) {
  const float* nf  = (const float*)d_in[0];
  const int*   ei  = (const int*)d_in[1];
  const float* W0  = (const float*)d_in[2];
  const float* b0  = (const float*)d_in[3];
  const float* W1  = (const float*)d_in[4];
  const float* b1  = (const float*)d_in[5];
  const float* W2  = (const float*)d_in[6];
  const float* b2  = (const float*)d_in[7];
  const float* g0  = (const float*)d_in[8];
  const float* be0 = (const float*)d_in[9];
  const float* g1  = (const float*)d_in[10];
  const float* be1 = (const float*)d_in[11];
  const float* g2  = (const float*)d_in[12];
  const float* be2 = (const float*)d_in[13];
  float* out = (float*)d_out;

  int N = in_sizes[0] / F_IN;   // 100000
  int E = in_sizes[1] / 2;      // 1600000
  const int* src = ei;
  const int* tgt = ei + E;
  int NB = (N + 255) >> BKT_SHIFT;        // 391 buckets
  int NCH = (E + 4095) / 4096;            // 391 chunks

  char* w = (char*)d_ws;
  auto al = [](size_t x) { return (x + 255) & ~(size_t)255; };
  int* bcnt     = (int*)w;      w += al(512 * 4);
  int* bOffs    = (int*)w;      w += al(512 * 4);
  int* bcur     = (int*)w;      w += al(512 * 4);
  int* deg      = (int*)w;      w += al((size_t)N * 4);
  int* offs     = (int*)w;      w += al((size_t)N * 4);
  int* csr      = (int*)w;      w += al((size_t)E * 4);
  unsigned* tmp = (unsigned*)w; w += al((size_t)E * 4);
  unsigned* nfb = (unsigned*)w; w += al((size_t)N * 32);        // bf16 [N][16]
  unsigned* x1  = (unsigned*)w; w += al((size_t)N * 256);       // bf16 CHUNKED [8][N][16]
  unsigned* axg = (unsigned*)w; w += al((size_t)N * 256);       // bf16 row-major [N][128]
  unsigned* xt2 = (unsigned*)w; w += al((size_t)N * 128);       // bf16 CHUNKED [4][N][16]
  unsigned* ybf = (unsigned*)w; w += al((size_t)N * 128);       // bf16 CHUNKED [4][N][16]

  hipMemsetAsync(bcnt, 0, 512 * 4, stream);

  // CSR build (bucketed counting sort; also produces deg/offs)
  k_bhist<<<256, 256, 0, stream>>>(tgt, bcnt, E, NB);
  k_bscan<<<1, 512, 0, stream>>>(bcnt, bOffs, bcur, NB);
  k_bin<<<NCH, 256, 0, stream>>>(src, tgt, bcur, tmp, E, NB);
  k_bucket<<<NB, 256, 0, stream>>>(tmp, bOffs, bcnt, deg, offs, csr, N);

  // input features -> padded bf16 [N][16]
  k_cvt<<<(N * 8 + 255) / 256, 256, 0, stream>>>(nf, nfb, N);

  // layer 0 fused: aggregate + linear+LN+ReLU -> chunked bf16 x1
  k_l0<<<(N + 7) / 8, 256, 0, stream>>>(nfb, csr, offs, deg, W0, b0, g0, be0, x1, N);

  // layer 1 aggregation: chunked gather (XCD-affine, lane-pair/node), row-major out
  k_agg128<<<8192, 256, 0, stream>>>(x1, csr, offs, deg, axg, N);

  // fused layer1 linear+LN+ReLU + layer2 linear (MFMA) -> chunked bf16 xt2
  k_mlp<<<512, 256, 0, stream>>>(axg, W1, b1, g1, be1, W2, b2, deg, xt2, N);

  // layer 2 aggregation (chunked) + final LN -> out
  k_agg64<<<3128 * 4, 256, 0, stream>>>(xt2, csr, offs, deg, ybf, N);
  k_ln64<<<(N + 31) / 32, 256, 0, stream>>>(ybf, g2, be2, out, N);
}